// Round 8
// baseline (352.983 us; speedup 1.0000x reference)
//
#include <hip/hip_runtime.h>
#include <hip/hip_fp16.h>
#include <math.h>
#include <stdint.h>

// MSDeformAttn. N=2, C=256, M=8, L=4, P=4, D=32, LEN=21760
// R8: occupancy-first. valproj/outproj: 16x64 waves, grid 2720, bounds(256,8),
//     barrier-free. desc: 16-query blocks (grid 680, 25KB LDS). gather as R7.

constexpr int NB  = 2;
constexpr int C   = 256;
constexpr int M   = 8;
constexpr int D   = 32;
constexpr int LEN = 21760;
constexpr int QCH = LEN / 4;   // 5440 queries per chunk (per batch)

typedef __attribute__((ext_vector_type(8))) short short8v;
typedef __attribute__((ext_vector_type(4))) float f32x4;

__device__ __forceinline__ short f2bf(float x) {
  uint32_t u = __float_as_uint(x);
  u = (u + 0x7fffu + ((u >> 16) & 1u)) >> 16;
  return (short)u;
}

// ---------------------------------------------------------------------------
// Prepack (all 4 weight mats in one launch): dst[c][k] = (bf16) src[k][c]
// ---------------------------------------------------------------------------
__global__ __launch_bounds__(256) void k_tcast4(
    const float* __restrict__ s0, const float* __restrict__ s1,
    const float* __restrict__ s2, const float* __restrict__ s3,
    short* __restrict__ d0, short* __restrict__ d1,
    short* __restrict__ d2, short* __restrict__ d3) {
  __shared__ float tile[32][33];
  const int z = blockIdx.z;
  const float* src = (z == 0) ? s0 : (z == 1) ? s1 : (z == 2) ? s2 : s3;
  short* dst = (z == 0) ? d0 : (z == 1) ? d1 : (z == 2) ? d2 : d3;
  const int ncols = (z == 2) ? 128 : 256;
  const int c0 = blockIdx.x * 32, k0 = blockIdx.y * 32;
  if (c0 >= ncols) return;
  const int t = threadIdx.x, tx = t & 31, ty = t >> 5;
#pragma unroll
  for (int i = 0; i < 4; ++i)
    tile[ty + i * 8][tx] = src[(size_t)(k0 + ty + i * 8) * ncols + c0 + tx];
  __syncthreads();
#pragma unroll
  for (int i = 0; i < 4; ++i)
    dst[(size_t)(c0 + ty + i * 8) * 256 + k0 + tx] = f2bf(tile[tx][ty + i * 8]);
}

// ---------------------------------------------------------------------------
// helpers
// ---------------------------------------------------------------------------
__device__ __forceinline__ short8v ldB(const short* __restrict__ WT, int col, int ks, int lane) {
  const int kidx = ks * 32 + ((lane >> 4) << 3);
  const int4 v = *(const int4*)(WT + (size_t)col * 256 + kidx);
  union { int4 i; short8v s; } u; u.i = v; return u.s;
}

// ---------------------------------------------------------------------------
// Kernel: value = bf16mm(input_flatten, WvT) + bv -> fp16 value[n][m][pix][d]
// Barrier-free; wave = 16 rows x 64 cols; grid 2720.
// ---------------------------------------------------------------------------
__global__ __launch_bounds__(256, 8) void k_valproj(
    const float* __restrict__ infl, const short* __restrict__ WvT,
    const float* __restrict__ bv, __half* __restrict__ value) {
  const int t = threadIdx.x, lane = t & 63, w = t >> 6;
  const int r0 = blockIdx.x * 16;
  const int c0 = w * 64;
  const int lr = lane & 15, lk = lane >> 4;

  f32x4 acc[4];
#pragma unroll
  for (int b = 0; b < 4; ++b) acc[b] = (f32x4){0.f, 0.f, 0.f, 0.f};

#pragma unroll
  for (int ks = 0; ks < 8; ++ks) {
    const float* ap = infl + (size_t)(r0 + lr) * C + ks * 32 + lk * 8;
    const float4 f0 = *(const float4*)ap;
    const float4 f1 = *(const float4*)(ap + 4);
    short8v af;
    af[0] = f2bf(f0.x); af[1] = f2bf(f0.y);
    af[2] = f2bf(f0.z); af[3] = f2bf(f0.w);
    af[4] = f2bf(f1.x); af[5] = f2bf(f1.y);
    af[6] = f2bf(f1.z); af[7] = f2bf(f1.w);
#pragma unroll
    for (int ct = 0; ct < 4; ++ct) {
      const short8v b = ldB(WvT, c0 + ct * 16 + lr, ks, lane);
      acc[ct] = __builtin_amdgcn_mfma_f32_16x16x32_bf16(af, b, acc[ct], 0, 0, 0);
    }
  }

  const int n = (blockIdx.x >= (LEN / 16)) ? 1 : 0;
  const int pixbase = r0 - n * LEN;
#pragma unroll
  for (int ct = 0; ct < 4; ++ct) {
    const int col = c0 + ct * 16 + lr;
    const float bb = bv[col];
    const int m = col >> 5, d = col & 31;
    __half* vp = value + ((size_t)(n * 8 + m) * LEN) * 32 + d;
#pragma unroll
    for (int r = 0; r < 4; ++r) {
      const int pix = pixbase + lk * 4 + r;
      vp[(size_t)pix * 32] = __float2half(acc[ct][r] + bb);
    }
  }
}

// ---------------------------------------------------------------------------
// Kernel: offsets/attn GEMM (bf16 MFMA) + softmax + descriptor build
// 16-query blocks, grid 680/launch, LDS ~24.5 KiB.
// Desc layout: descD[((n*8+m)*QCH + q)*16 + j]  (slice-major)
// ---------------------------------------------------------------------------
__global__ __launch_bounds__(256, 4) void k_desc(
    const float* __restrict__ query, const float* __restrict__ refp,
    const short* __restrict__ WdT, const float* __restrict__ boff,
    const float* __restrict__ battn, uint4* __restrict__ descD, int qbase) {
  __shared__ __align__(16) char smem[25088];
  char*  smA  = smem;                       // [16][512] bf16 A-tile (8 KiB)
  float* offs = (float*)smem;               // [16][256] f32 (16 KiB, aliases smA)
  float* attw = (float*)(smem + 16384);     // [16][128] f32 (8 KiB)
  float* refs = (float*)(smem + 24576);     // [16][8]   (512 B)

  const int t = threadIdx.x, lane = t & 63, w = t >> 6;
  const int n   = blockIdx.x / 340;
  const int q0c = (blockIdx.x % 340) * 16;
  const size_t qrow = (size_t)n * LEN + qbase + q0c;

  if (t < 128) refs[t] = refp[qrow * 8 + t];
  // stage 16 rows x 256 cols fp32 -> bf16 swizzled LDS
  {
    const int r = t >> 4, seg = t & 15;   // 16 segs x 16 floats
    const float4* s = (const float4*)(query + qrow * C + (size_t)r * C + seg * 16);
    short v[16];
#pragma unroll
    for (int i = 0; i < 4; ++i) {
      float4 f = s[i];
      v[i * 4 + 0] = f2bf(f.x); v[i * 4 + 1] = f2bf(f.y);
      v[i * 4 + 2] = f2bf(f.z); v[i * 4 + 3] = f2bf(f.w);
    }
#pragma unroll
    for (int i = 0; i < 2; ++i) {
      const int kb = (seg * 16 + i * 8) * 2;
      *(int4*)(smA + r * 512 + (kb ^ ((r & 7) << 4))) = ((const int4*)v)[i];
    }
  }
  __syncthreads();

  f32x4 acc[6];
#pragma unroll
  for (int b = 0; b < 6; ++b) acc[b] = (f32x4){0.f, 0.f, 0.f, 0.f};
  const int c0w = w * 96;
#pragma unroll
  for (int ks = 0; ks < 8; ++ks) {
    const int row = lane & 15;
    const int kb  = ks * 64 + ((lane >> 4) << 4);
    const int4 av = *(const int4*)(smA + row * 512 + (kb ^ ((row & 7) << 4)));
    union { int4 i; short8v s; } ua; ua.i = av;
    const short8v a0 = ua.s;
#pragma unroll
    for (int ct = 0; ct < 6; ++ct) {
      const short8v b = ldB(WdT, c0w + ct * 16 + (lane & 15), ks, lane);
      acc[ct] = __builtin_amdgcn_mfma_f32_16x16x32_bf16(a0, b, acc[ct], 0, 0, 0);
    }
  }
  __syncthreads();   // all LDS A reads complete before aliasing writes

#pragma unroll
  for (int ct = 0; ct < 6; ++ct) {
    const int col = c0w + ct * 16 + (lane & 15);
    const float bb = (col < 256) ? boff[col] : battn[col - 256];
#pragma unroll
    for (int r = 0; r < 4; ++r) {
      const int row = ((lane >> 4) << 2) + r;
      const float vv = acc[ct][r] + bb;
      if (col < 256) offs[row * 256 + col] = vv;
      else           attw[row * 128 + col - 256] = vv;
    }
  }
  __syncthreads();

  // softmax over 16 per (q, m): 128 tasks
  if (t < 128) {
    const int q = t >> 3, m = t & 7;
    float v[16], mx = -1e30f;
#pragma unroll
    for (int j = 0; j < 16; ++j) { v[j] = attw[q * 128 + m * 16 + j]; mx = fmaxf(mx, v[j]); }
    float s = 0.f;
#pragma unroll
    for (int j = 0; j < 16; ++j) { v[j] = __expf(v[j] - mx); s += v[j]; }
    const float inv = 1.f / s;
#pragma unroll
    for (int j = 0; j < 16; ++j) attw[q * 128 + m * 16 + j] = v[j] * inv;
  }
  __syncthreads();

  // descriptor build: 16 q x 128 (m,j) = 2048, 8 per thread
#pragma unroll
  for (int i = 0; i < 8; ++i) {
    const int e = i * 256 + t;
    const int q = e >> 7, rem = e & 127;
    const int m = rem >> 4, j = rem & 15, l = j >> 2;
    const int jo = m * 16 + j;
    const float ox = offs[q * 256 + 2 * jo], oy = offs[q * 256 + 2 * jo + 1];
    const float aw = attw[q * 128 + jo];
    const float rx = refs[q * 8 + l * 2 + 0], ry = refs[q * 8 + l * 2 + 1];
    const int W = 128 >> l;
    const int st_l = ((16384 - (16384 >> (2 * l))) * 4) / 3;  // 0,16384,20480,21504
    const float x = rx * (float)W + ox - 0.5f;
    const float y = ry * (float)W + oy - 0.5f;
    const float x0f = floorf(x), y0f = floorf(y);
    const float fx = x - x0f, fy = y - y0f;
    const int x0 = (int)x0f, y0 = (int)y0f;
    const int x1 = x0 + 1, y1 = y0 + 1;
    const int x0c = min(max(x0, 0), W - 1), x1c = min(max(x1, 0), W - 1);
    const int y0c = min(max(y0, 0), W - 1), y1c = min(max(y1, 0), W - 1);
    float wx0 = 1.f - fx, wx1 = fx, wy0 = 1.f - fy, wy1 = fy;
    if (x0 < 0 || x0 >= W) wx0 = 0.f;
    if (x1 < 0 || x1 >= W) wx1 = 0.f;
    if (y0 < 0 || y0 >= W) wy0 = 0.f;
    if (y1 < 0 || y1 >= W) wy1 = 0.f;
    uint4 dsc;
    dsc.x = (uint32_t)(st_l + y0c * W + x0c) | ((uint32_t)(st_l + y0c * W + x1c) << 16);
    dsc.y = (uint32_t)(st_l + y1c * W + x0c) | ((uint32_t)(st_l + y1c * W + x1c) << 16);
    union { __half2 h; uint32_t u; } p0, p1;
    p0.h = __floats2half2_rn(wx0 * wy0 * aw, wx1 * wy0 * aw);
    p1.h = __floats2half2_rn(wx0 * wy1 * aw, wx1 * wy1 * aw);
    dsc.z = p0.u;
    dsc.w = p1.u;
    descD[((size_t)(n * 8 + m) * QCH + q0c + q) * 16 + j] = dsc;
  }
}

// ---------------------------------------------------------------------------
// Kernel: pure gather, m-partitioned + XCD-swizzled, slice-major desc.
// ---------------------------------------------------------------------------
#define ACC4(RV, WW)                                        \
  {                                                         \
    const float2 f0 = __half22float2(RV.h[0]);              \
    const float2 f1 = __half22float2(RV.h[1]);              \
    const float2 f2 = __half22float2(RV.h[2]);              \
    const float2 f3 = __half22float2(RV.h[3]);              \
    a0 += (WW) * f0.x; a1 += (WW) * f0.y;                   \
    a2 += (WW) * f1.x; a3 += (WW) * f1.y;                   \
    a4 += (WW) * f2.x; a5 += (WW) * f2.y;                   \
    a6 += (WW) * f3.x; a7 += (WW) * f3.y;                   \
  }

__global__ __launch_bounds__(256, 8) void k_gather(
    const uint4* __restrict__ descD, const __half* __restrict__ value,
    short* __restrict__ accB, int qbase) {
  const int t = threadIdx.x;
  const int d4 = t & 3, ql = t >> 2;          // 64 queries per block
  const int bid = blockIdx.x;
  const int s = bid & 15, qc = bid >> 4;      // slice, query-chunk (85)
  const int n = s >> 3, m = s & 7;
  const int q = qc * 64 + ql;                 // within chunk
  const uint4* dp = descD + ((size_t)(n * 8 + m) * QCH + q) * 16;
  const char* vb = (const char*)value +
                   (size_t)((n * 8 + m) * LEN) * 64 + d4 * 16;

  float a0 = 0.f, a1 = 0.f, a2 = 0.f, a3 = 0.f;
  float a4 = 0.f, a5 = 0.f, a6 = 0.f, a7 = 0.f;

#pragma unroll 4
  for (int j = 0; j < 16; ++j) {
    const uint4 dsc = dp[j];
    const uint32_t i00 = dsc.x & 0xffffu, i01 = dsc.x >> 16;
    const uint32_t i10 = dsc.y & 0xffffu, i11 = dsc.y >> 16;
    union { uint32_t u; __half2 h; } pz, pw;
    pz.u = dsc.z; pw.u = dsc.w;
    const float2 wA = __half22float2(pz.h);
    const float2 wB = __half22float2(pw.h);
    union { uint4 v; __half2 h[4]; } r0, r1, r2, r3;
    r0.v = *(const uint4*)(vb + (size_t)i00 * 64u);
    r1.v = *(const uint4*)(vb + (size_t)i01 * 64u);
    r2.v = *(const uint4*)(vb + (size_t)i10 * 64u);
    r3.v = *(const uint4*)(vb + (size_t)i11 * 64u);
    ACC4(r0, wA.x);
    ACC4(r1, wA.y);
    ACC4(r2, wB.x);
    ACC4(r3, wB.y);
  }
  short8v o;
  o[0] = f2bf(a0); o[1] = f2bf(a1); o[2] = f2bf(a2); o[3] = f2bf(a3);
  o[4] = f2bf(a4); o[5] = f2bf(a5); o[6] = f2bf(a6); o[7] = f2bf(a7);
  *(short8v*)(accB + ((size_t)n * LEN + qbase + q) * 256 + m * 32 + d4 * 8) = o;
}

// ---------------------------------------------------------------------------
// Kernel: out = bf16mm(acc, WoT) + bo (fp32 out). 16x64 waves, grid 2720.
// ---------------------------------------------------------------------------
__global__ __launch_bounds__(256, 8) void k_outproj(
    const short* __restrict__ accB, const short* __restrict__ WoT,
    const float* __restrict__ bo, float* __restrict__ out) {
  const int t = threadIdx.x, lane = t & 63, w = t >> 6;
  const int r0 = blockIdx.x * 16;
  const int c0 = w * 64;
  const int lr = lane & 15, lk = lane >> 4;

  f32x4 acc[4];
#pragma unroll
  for (int b = 0; b < 4; ++b) acc[b] = (f32x4){0.f, 0.f, 0.f, 0.f};

#pragma unroll
  for (int ks = 0; ks < 8; ++ks) {
    const int4 v = *(const int4*)(accB + (size_t)(r0 + lr) * C + ks * 32 + lk * 8);
    union { int4 i; short8v s; } u; u.i = v;
    const short8v af = u.s;
#pragma unroll
    for (int ct = 0; ct < 4; ++ct) {
      const short8v b = ldB(WoT, c0 + ct * 16 + lr, ks, lane);
      acc[ct] = __builtin_amdgcn_mfma_f32_16x16x32_bf16(af, b, acc[ct], 0, 0, 0);
    }
  }

#pragma unroll
  for (int ct = 0; ct < 4; ++ct) {
    const int col = c0 + ct * 16 + lr;
    const float bb = bo[col];
#pragma unroll
    for (int r = 0; r < 4; ++r) {
      const int row = r0 + lk * 4 + r;
      out[(size_t)row * C + col] = acc[ct][r] + bb;
    }
  }
}

// ---------------------------------------------------------------------------
extern "C" void kernel_launch(void* const* d_in, const int* in_sizes, int n_in,
                              void* d_out, int out_size, void* d_ws, size_t ws_size,
                              hipStream_t stream) {
  const float* query = (const float*)d_in[0];
  const float* refp  = (const float*)d_in[1];
  const float* infl  = (const float*)d_in[2];
  const float* Woff  = (const float*)d_in[3];
  const float* boff  = (const float*)d_in[4];
  const float* Wattn = (const float*)d_in[5];
  const float* battn = (const float*)d_in[6];
  const float* Wval  = (const float*)d_in[7];
  const float* bval  = (const float*)d_in[8];
  const float* Wout  = (const float*)d_in[9];
  const float* bout  = (const float*)d_in[10];
  float* out = (float*)d_out;

  char* ws = (char*)d_ws;
  __half* value = (__half*)ws;                   // 22,282,240 B
  short*  accB  = (short*)(ws + 22282240);       // 22,282,240 B
  uint4*  descD = (uint4*)(ws + 44564480);       // 22,282,240 B
  short*  WvT   = (short*)(ws + 66846720);       // 131,072 B
  short*  WdT   = (short*)(ws + 66977792);       // 196,608 B
  short*  WoT   = (short*)(ws + 67174400);       // 131,072 B  (total 67.3 MB)

  k_tcast4<<<dim3(8, 8, 4), 256, 0, stream>>>(
      Wval, Woff, Wattn, Wout, WvT, WdT, WdT + (size_t)256 * 256, WoT);

  k_valproj<<<(NB * LEN) / 16, 256, 0, stream>>>(infl, WvT, bval, value);

  for (int c = 0; c < 4; ++c) {
    k_desc<<<2 * (QCH / 16), 256, 0, stream>>>(query, refp, WdT, boff, battn,
                                               descD, c * QCH);
    k_gather<<<16 * (QCH / 64), 256, 0, stream>>>(descD, value, accB, c * QCH);
  }

  k_outproj<<<(NB * LEN) / 16, 256, 0, stream>>>(accB, WoT, bout, out);
}

// Round 10
// 196.657 us; speedup vs baseline: 1.7949x; 1.7949x over previous
//
#include <hip/hip_runtime.h>
#include <hip/hip_fp16.h>
#include <math.h>
#include <stdint.h>

// MSDeformAttn. N=2, C=256, M=8, L=4, P=4, D=32, LEN=21760
// R10: R9 with fixed k_wpack lane decomposition (lr=lane&15, lk=lane>>4)
//      and wider fixed-point clamp in descriptors.

constexpr int NB  = 2;
constexpr int C   = 256;
constexpr int M   = 8;
constexpr int D   = 32;
constexpr int LEN = 21760;
constexpr int QCHc = LEN / 2;   // 10880 queries per chunk (per batch)

typedef __attribute__((ext_vector_type(8))) short short8v;
typedef __attribute__((ext_vector_type(4))) float f32x4;

__device__ __forceinline__ short f2bf(float x) {
  uint32_t u = __float_as_uint(x);
  u = (u + 0x7fffu + ((u >> 16) & 1u)) >> 16;
  return (short)u;
}

// ---------------------------------------------------------------------------
// Weight prepack into per-fragment-coalesced layout:
// WP[((ks*NCG+cg)*64 + lane)*8 + e] = W[ks*32 + (lane>>4)*8 + e][cg*16 + (lane&15)]
// job y: 0=Wval(256), 1=Woff|Wattn(384), 2=Wout(256)
// ---------------------------------------------------------------------------
__global__ __launch_bounds__(256) void k_wpack(
    const float* __restrict__ Wval, const float* __restrict__ Woff,
    const float* __restrict__ Wattn, const float* __restrict__ Wout,
    short* __restrict__ WvP, short* __restrict__ WdP, short* __restrict__ WoP) {
  const int job = blockIdx.y;
  const int ncols = (job == 1) ? 384 : 256;
  const int NCG = ncols / 16;
  const int elems = 256 * ncols;
  const int idx = blockIdx.x * 256 + threadIdx.x;
  if (idx >= elems) return;
  const int e    = idx & 7;
  const int lane = (idx >> 3) & 63;
  const int lr = lane & 15, lk = lane >> 4;   // FIXED: matches ldBP/MFMA frag
  const int cgks = idx >> 9;
  const int cg = cgks % NCG, ks = cgks / NCG;
  const int k = ks * 32 + lk * 8 + e;
  const int col = cg * 16 + lr;
  float v;
  if (job == 0)      v = Wval[(size_t)k * 256 + col];
  else if (job == 2) v = Wout[(size_t)k * 256 + col];
  else               v = (col < 256) ? Woff[(size_t)k * 256 + col]
                                     : Wattn[(size_t)k * 128 + col - 256];
  short* dst = (job == 0) ? WvP : (job == 1) ? WdP : WoP;
  dst[idx] = f2bf(v);
}

__device__ __forceinline__ short8v ldBP(const short* __restrict__ WP, int NCG,
                                        int cg, int ks, int lane) {
  const int4 v = *(const int4*)(WP + ((size_t)((ks * NCG + cg) * 64 + lane)) * 8);
  union { int4 i; short8v s; } u; u.i = v; return u.s;
}

// ---------------------------------------------------------------------------
// LDS staging (32 rows x 256 k, bf16, XOR-swizzled) + A fragment loads
// ---------------------------------------------------------------------------
__device__ __forceinline__ void stage_cast(const float* __restrict__ p, char* sm, int t) {
  const int r = t >> 3, seg = t & 7;
  const float4* s = (const float4*)(p + (size_t)r * C + seg * 32);
  short v[32];
#pragma unroll
  for (int i = 0; i < 8; ++i) {
    float4 f = s[i];
    v[i * 4 + 0] = f2bf(f.x); v[i * 4 + 1] = f2bf(f.y);
    v[i * 4 + 2] = f2bf(f.z); v[i * 4 + 3] = f2bf(f.w);
  }
#pragma unroll
  for (int i = 0; i < 4; ++i) {
    const int kb = (seg * 32 + i * 8) * 2;
    *(int4*)(sm + r * 512 + (kb ^ ((r & 7) << 4))) = ((const int4*)v)[i];
  }
}

__device__ __forceinline__ void stage_bf16(const short* __restrict__ p, char* sm, int t) {
  const int r = t >> 3, seg = t & 7;
  const int4* s = (const int4*)(p + (size_t)r * C + seg * 32);
#pragma unroll
  for (int i = 0; i < 4; ++i) {
    const int kb = (seg * 32 + i * 8) * 2;
    *(int4*)(sm + r * 512 + (kb ^ ((r & 7) << 4))) = s[i];
  }
}

__device__ __forceinline__ short8v ldsA(const char* sm, int lane, int rt, int ks) {
  const int row = rt * 16 + (lane & 15);
  const int kb  = ks * 64 + ((lane >> 4) << 4);
  const int4 v = *(const int4*)(sm + row * 512 + (kb ^ ((row & 7) << 4)));
  union { int4 i; short8v s; } u; u.i = v; return u.s;
}

#define MFMA __builtin_amdgcn_mfma_f32_16x16x32_bf16

// ---------------------------------------------------------------------------
// GEMM body shared by valproj/outproj: 32 rows x 256 cols per block, 4 waves.
// All 16 A frags in regs; B double-buffered 8-deep per ct.
// ---------------------------------------------------------------------------
#define GEMM_BODY(WP)                                                       \
  short8v a[2][8];                                                          \
  _Pragma("unroll") for (int rt = 0; rt < 2; ++rt)                          \
  _Pragma("unroll") for (int ks = 0; ks < 8; ++ks)                          \
      a[rt][ks] = ldsA(smA, lane, rt, ks);                                  \
  f32x4 acc[2][4];                                                          \
  _Pragma("unroll") for (int rt = 0; rt < 2; ++rt)                          \
  _Pragma("unroll") for (int ct = 0; ct < 4; ++ct)                          \
      acc[rt][ct] = (f32x4){0.f, 0.f, 0.f, 0.f};                            \
  short8v b0[8], b1[8];                                                     \
  _Pragma("unroll") for (int ks = 0; ks < 8; ++ks)                          \
      b0[ks] = ldBP(WP, 16, cg0 + 0, ks, lane);                             \
  _Pragma("unroll") for (int ks = 0; ks < 8; ++ks)                          \
      b1[ks] = ldBP(WP, 16, cg0 + 1, ks, lane);                             \
  _Pragma("unroll") for (int ks = 0; ks < 8; ++ks) {                        \
    acc[0][0] = MFMA(a[0][ks], b0[ks], acc[0][0], 0, 0, 0);                 \
    acc[1][0] = MFMA(a[1][ks], b0[ks], acc[1][0], 0, 0, 0);                 \
  }                                                                         \
  _Pragma("unroll") for (int ks = 0; ks < 8; ++ks)                          \
      b0[ks] = ldBP(WP, 16, cg0 + 2, ks, lane);                             \
  _Pragma("unroll") for (int ks = 0; ks < 8; ++ks) {                        \
    acc[0][1] = MFMA(a[0][ks], b1[ks], acc[0][1], 0, 0, 0);                 \
    acc[1][1] = MFMA(a[1][ks], b1[ks], acc[1][1], 0, 0, 0);                 \
  }                                                                         \
  _Pragma("unroll") for (int ks = 0; ks < 8; ++ks)                          \
      b1[ks] = ldBP(WP, 16, cg0 + 3, ks, lane);                             \
  _Pragma("unroll") for (int ks = 0; ks < 8; ++ks) {                        \
    acc[0][2] = MFMA(a[0][ks], b0[ks], acc[0][2], 0, 0, 0);                 \
    acc[1][2] = MFMA(a[1][ks], b0[ks], acc[1][2], 0, 0, 0);                 \
  }                                                                         \
  _Pragma("unroll") for (int ks = 0; ks < 8; ++ks) {                        \
    acc[0][3] = MFMA(a[0][ks], b1[ks], acc[0][3], 0, 0, 0);                 \
    acc[1][3] = MFMA(a[1][ks], b1[ks], acc[1][3], 0, 0, 0);                 \
  }

// ---------------------------------------------------------------------------
// Kernel: value = bf16mm(input_flatten, WvP) + bv -> fp16 value[n][m][pix][d]
// ---------------------------------------------------------------------------
__global__ __launch_bounds__(256, 2) void k_valproj(
    const float* __restrict__ infl, const short* __restrict__ WvP,
    const float* __restrict__ bv, __half* __restrict__ value) {
  __shared__ __align__(16) char smA[16384];
  const int t = threadIdx.x, lane = t & 63, w = t >> 6;
  const int r0 = blockIdx.x * 32;
  stage_cast(infl + (size_t)r0 * C, smA, t);
  __syncthreads();
  const int cg0 = w * 4;
  const int lr = lane & 15, lk = lane >> 4;
  GEMM_BODY(WvP)

  const int n = (blockIdx.x >= (LEN / 32)) ? 1 : 0;
  const int pixbase = r0 - n * LEN;
#pragma unroll
  for (int ct = 0; ct < 4; ++ct) {
    const int col = (cg0 + ct) * 16 + lr;
    const float bb = bv[col];
    const int m = col >> 5, d = col & 31;
    __half* vp = value + ((size_t)(n * 8 + m) * LEN) * 32 + d;
#pragma unroll
    for (int rt = 0; rt < 2; ++rt)
#pragma unroll
      for (int r = 0; r < 4; ++r) {
        const int pix = pixbase + rt * 16 + lk * 4 + r;
        vp[(size_t)pix * 32] = __float2half(acc[rt][ct][r] + bb);
      }
  }
}

// ---------------------------------------------------------------------------
// Kernel: out = bf16mm(accB, WoP) + bo (fp32 out)
// ---------------------------------------------------------------------------
__global__ __launch_bounds__(256, 2) void k_outproj(
    const short* __restrict__ accB, const short* __restrict__ WoP,
    const float* __restrict__ bo, float* __restrict__ out) {
  __shared__ __align__(16) char smA[16384];
  const int t = threadIdx.x, lane = t & 63, w = t >> 6;
  const int r0 = blockIdx.x * 32;
  stage_bf16(accB + (size_t)r0 * C, smA, t);
  __syncthreads();
  const int cg0 = w * 4;
  const int lr = lane & 15, lk = lane >> 4;
  GEMM_BODY(WoP)

#pragma unroll
  for (int ct = 0; ct < 4; ++ct) {
    const int col = (cg0 + ct) * 16 + lr;
    const float bb = bo[col];
#pragma unroll
    for (int rt = 0; rt < 2; ++rt)
#pragma unroll
      for (int r = 0; r < 4; ++r) {
        const int row = r0 + rt * 16 + lk * 4 + r;
        out[(size_t)row * C + col] = acc[rt][ct][r] + bb;
      }
  }
}

// ---------------------------------------------------------------------------
// Kernel: offsets/attn GEMM + softmax + 8B fixed-point descriptor build
// descD[((n*8+m)*QCHc + q)*16 + j] : uint2 {xfix|(yfix<<16), aw_half}
// fixed point: (coord + 8) * 128, coord clamped to [-8, 503]
// ---------------------------------------------------------------------------
__global__ __launch_bounds__(256, 3) void k_desc(
    const float* __restrict__ query, const float* __restrict__ refp,
    const short* __restrict__ WdP, const float* __restrict__ boff,
    const float* __restrict__ battn, uint2* __restrict__ descD, int qbase) {
  __shared__ __align__(16) char smem[50176];
  char*  smA  = smem;                       // [32][512] bf16 A-tile
  float* offs = (float*)smem;               // [32][256] (aliases smA; used later)
  float* attw = (float*)(smem + 32768);     // [32][128]
  float* refs = (float*)(smem + 49152);     // [32][8]

  const int t = threadIdx.x, lane = t & 63, w = t >> 6;
  const int n   = blockIdx.x / 340;
  const int q0c = (blockIdx.x % 340) * 32;
  const size_t qrow = (size_t)n * LEN + qbase + q0c;

  refs[t] = refp[qrow * 8 + t];
  stage_cast(query + qrow * C, smA, t);
  __syncthreads();

  f32x4 acc[2][6];
#pragma unroll
  for (int a = 0; a < 2; ++a)
#pragma unroll
    for (int b = 0; b < 6; ++b) acc[a][b] = (f32x4){0.f, 0.f, 0.f, 0.f};
  const int cgb = w * 6;
#pragma unroll
  for (int ks = 0; ks < 8; ++ks) {
    const short8v a0 = ldsA(smA, lane, 0, ks);
    const short8v a1 = ldsA(smA, lane, 1, ks);
#pragma unroll
    for (int ct = 0; ct < 6; ++ct) {
      const short8v b = ldBP(WdP, 24, cgb + ct, ks, lane);
      acc[0][ct] = MFMA(a0, b, acc[0][ct], 0, 0, 0);
      acc[1][ct] = MFMA(a1, b, acc[1][ct], 0, 0, 0);
    }
  }
  __syncthreads();   // all LDS A reads complete before aliasing writes

#pragma unroll
  for (int ct = 0; ct < 6; ++ct) {
    const int col = (cgb + ct) * 16 + (lane & 15);
    const float bb = (col < 256) ? boff[col] : battn[col - 256];
#pragma unroll
    for (int rt = 0; rt < 2; ++rt)
#pragma unroll
      for (int r = 0; r < 4; ++r) {
        const int row = rt * 16 + ((lane >> 4) << 2) + r;
        const float vv = acc[rt][ct][r] + bb;
        if (col < 256) offs[row * 256 + col] = vv;
        else           attw[row * 128 + col - 256] = vv;
      }
  }
  __syncthreads();

  // softmax over 16 per (q, m): 256 tasks
  {
    const int q = t >> 3, m = t & 7;
    float v[16], mx = -1e30f;
#pragma unroll
    for (int j = 0; j < 16; ++j) { v[j] = attw[q * 128 + m * 16 + j]; mx = fmaxf(mx, v[j]); }
    float s = 0.f;
#pragma unroll
    for (int j = 0; j < 16; ++j) { v[j] = __expf(v[j] - mx); s += v[j]; }
    const float inv = 1.f / s;
#pragma unroll
    for (int j = 0; j < 16; ++j) attw[q * 128 + m * 16 + j] = v[j] * inv;
  }
  __syncthreads();

  // descriptor build: 32 q x 128 (m,j) = 4096, 16 per thread, coalesced
#pragma unroll
  for (int i = 0; i < 16; ++i) {
    const int e = i * 256 + t;
    const int q = e >> 7, rem = e & 127;
    const int m = rem >> 4, j = rem & 15, l = j >> 2;
    const int jo = m * 16 + j;
    const float ox = offs[q * 256 + 2 * jo], oy = offs[q * 256 + 2 * jo + 1];
    const float aw = attw[q * 128 + jo];
    const float rx = refs[q * 8 + l * 2 + 0], ry = refs[q * 8 + l * 2 + 1];
    const int W = 128 >> l;
    const float x = rx * (float)W + ox - 0.5f;
    const float y = ry * (float)W + oy - 0.5f;
    const float xc = fminf(fmaxf(x, -8.f), 503.f);
    const float yc = fminf(fmaxf(y, -8.f), 503.f);
    const uint32_t xfix = (uint32_t)((xc + 8.f) * 128.f + 0.5f);
    const uint32_t yfix = (uint32_t)((yc + 8.f) * 128.f + 0.5f);
    uint2 dsc;
    dsc.x = xfix | (yfix << 16);
    dsc.y = (uint32_t)__half_as_ushort(__float2half_rn(aw));
    descD[((size_t)(n * 8 + m) * QCHc + q0c + q) * 16 + j] = dsc;
  }
}

// ---------------------------------------------------------------------------
// Kernel: pure gather; recompute corners from 8B descriptors.
// ---------------------------------------------------------------------------
#define ACC4(RV, WW)                                        \
  {                                                         \
    const float2 f0 = __half22float2(RV.h[0]);              \
    const float2 f1 = __half22float2(RV.h[1]);              \
    const float2 f2 = __half22float2(RV.h[2]);              \
    const float2 f3 = __half22float2(RV.h[3]);              \
    a0 += (WW) * f0.x; a1 += (WW) * f0.y;                   \
    a2 += (WW) * f1.x; a3 += (WW) * f1.y;                   \
    a4 += (WW) * f2.x; a5 += (WW) * f2.y;                   \
    a6 += (WW) * f3.x; a7 += (WW) * f3.y;                   \
  }

__global__ __launch_bounds__(256, 8) void k_gather(
    const uint2* __restrict__ descD, const __half* __restrict__ value,
    short* __restrict__ accB, int qbase) {
  const int t = threadIdx.x;
  const int d4 = t & 3, ql = t >> 2;          // 64 queries per block
  const int bid = blockIdx.x;
  const int s = bid & 15, qc = bid >> 4;      // slice, query-chunk (170)
  const int n = s >> 3, m = s & 7;
  const int q = qc * 64 + ql;                 // within chunk
  const uint2* dp = descD + ((size_t)(n * 8 + m) * QCHc + q) * 16;
  const char* vb = (const char*)value +
                   (size_t)((n * 8 + m) * LEN) * 64 + d4 * 16;

  float a0 = 0.f, a1 = 0.f, a2 = 0.f, a3 = 0.f;
  float a4 = 0.f, a5 = 0.f, a6 = 0.f, a7 = 0.f;

#pragma unroll
  for (int j = 0; j < 16; ++j) {
    const int l = j >> 2;
    const int W = 128 >> l;
    const int stl = (l == 0) ? 0 : (l == 1) ? 16384 : (l == 2) ? 20480 : 21504;
    const uint2 dsc = dp[j];
    const int xf = (int)(dsc.x & 0xffffu), yf = (int)(dsc.x >> 16);
    const float aw = __half2float(__ushort_as_half((unsigned short)(dsc.y & 0xffffu)));
    const int xi = (xf >> 7) - 8, yi = (yf >> 7) - 8;
    const float fx = (float)(xf & 127) * 0.0078125f;
    const float fy = (float)(yf & 127) * 0.0078125f;
    float wx0 = 1.f - fx, wx1 = fx, wy0 = 1.f - fy, wy1 = fy;
    if (xi < 0 || xi >= W)         wx0 = 0.f;
    if (xi + 1 < 0 || xi + 1 >= W) wx1 = 0.f;
    if (yi < 0 || yi >= W)         wy0 = 0.f;
    if (yi + 1 < 0 || yi + 1 >= W) wy1 = 0.f;
    const int x0c = min(max(xi, 0), W - 1), x1c = min(max(xi + 1, 0), W - 1);
    const int y0c = min(max(yi, 0), W - 1), y1c = min(max(yi + 1, 0), W - 1);
    const int i00 = stl + y0c * W + x0c, i01 = stl + y0c * W + x1c;
    const int i10 = stl + y1c * W + x0c, i11 = stl + y1c * W + x1c;
    const float w00 = wx0 * wy0 * aw, w01 = wx1 * wy0 * aw;
    const float w10 = wx0 * wy1 * aw, w11 = wx1 * wy1 * aw;
    union { uint4 v; __half2 h[4]; } r0, r1, r2, r3;
    r0.v = *(const uint4*)(vb + (size_t)i00 * 64u);
    r1.v = *(const uint4*)(vb + (size_t)i01 * 64u);
    r2.v = *(const uint4*)(vb + (size_t)i10 * 64u);
    r3.v = *(const uint4*)(vb + (size_t)i11 * 64u);
    ACC4(r0, w00);
    ACC4(r1, w01);
    ACC4(r2, w10);
    ACC4(r3, w11);
  }
  short8v o;
  o[0] = f2bf(a0); o[1] = f2bf(a1); o[2] = f2bf(a2); o[3] = f2bf(a3);
  o[4] = f2bf(a4); o[5] = f2bf(a5); o[6] = f2bf(a6); o[7] = f2bf(a7);
  *(short8v*)(accB + ((size_t)n * LEN + qbase + q) * 256 + m * 32 + d4 * 8) = o;
}

// ---------------------------------------------------------------------------
extern "C" void kernel_launch(void* const* d_in, const int* in_sizes, int n_in,
                              void* d_out, int out_size, void* d_ws, size_t ws_size,
                              hipStream_t stream) {
  const float* query = (const float*)d_in[0];
  const float* refp  = (const float*)d_in[1];
  const float* infl  = (const float*)d_in[2];
  const float* Woff  = (const float*)d_in[3];
  const float* boff  = (const float*)d_in[4];
  const float* Wattn = (const float*)d_in[5];
  const float* battn = (const float*)d_in[6];
  const float* Wval  = (const float*)d_in[7];
  const float* bval  = (const float*)d_in[8];
  const float* Wout  = (const float*)d_in[9];
  const float* bout  = (const float*)d_in[10];
  float* out = (float*)d_out;

  char* ws = (char*)d_ws;
  __half* value = (__half*)ws;                   // 22,282,240 B
  short*  accB  = (short*)(ws + 22282240);       // 22,282,240 B
  uint2*  desc8 = (uint2*)(ws + 44564480);       // 22,282,240 B (one chunk)
  short*  WvP   = (short*)(ws + 66846720);       // 131,072 B
  short*  WdP   = (short*)(ws + 66977792);       // 196,608 B
  short*  WoP   = (short*)(ws + 67174400);       // 131,072 B  (total 67.3 MB)

  k_wpack<<<dim3(384, 3), 256, 0, stream>>>(Wval, Woff, Wattn, Wout,
                                            WvP, WdP, WoP);

  k_valproj<<<(NB * LEN) / 32, 256, 0, stream>>>(infl, WvP, bval, value);

  for (int c = 0; c < 2; ++c) {
    k_desc<<<NB * (QCHc / 32), 256, 0, stream>>>(query, refp, WdP, boff, battn,
                                                 desc8, c * QCHc);
    k_gather<<<16 * (QCHc / 64), 256, 0, stream>>>(desc8, value, accB, c * QCHc);
  }

  k_outproj<<<(NB * LEN) / 32, 256, 0, stream>>>(accB, WoP, bout, out);
}